// Round 6
// baseline (477.348 us; speedup 1.0000x reference)
//
#include <hip/hip_runtime.h>
#include <math.h>

// StableSinkhornKnopp: B=16384 x K=1024 fp32.
// Q[k,b] = s * E[b,k] * r[k] * c[b],  E = exp((x-M')*20), M' = sampled max
// (max shift cancels in all normalizations; sample within ~0.5 of true max).
// E cached once as bf16 (32 MiB in ws). 5 dispatches:
//   K1 smax+zero -> K2 exp+R0 (+last-block: s,r1) -> K3 col c1,R1 (+r2)
//   -> K3 col c2,R2 (+r3) -> K4 final c3 + out.
// r/s handoff via last-block reduction (counter + threadfence); every block
// reads r at kernel START and increments the counter at its END, so the
// last block's r overwrite cannot race any reader.

namespace {
constexpr int B_ROWS = 16384;
constexpr int K_COLS = 1024;
constexpr float INV_EPS = 20.0f;   // 1/0.05
constexpr float STAB = 1e-9f;
constexpr int NSPREAD = 32;        // atomic accumulator spread

// ws float offsets
constexpr int OFF_M    = 0;        // sampled max (int-ordered float)
constexpr int OFF_S    = 1;        // s = 1/(sum+eps)
constexpr int OFF_CNT  = 8;        // 3 ints (int-view of ws)
constexpr int OFF_R    = 1024;     // r vector, 1024
constexpr int OFF_RACC = 2048;     // 3 x NSPREAD x 1024 = 98304 floats
constexpr int OFF_C    = 100352;   // c vector, 16384
constexpr size_t EB_BYTE_OFF = 1u << 20;  // bf16 E at ws+1MiB, 32 MiB
}

__device__ inline unsigned bf16rne(float f) {
  unsigned u = __float_as_uint(f);
  return (u + 0x7FFFu + ((u >> 16) & 1u)) >> 16;
}
__device__ inline float bf16tof(unsigned h) { return __uint_as_float(h << 16); }

// ---- K1: zero RACC+counters, sampled max (4 MiB in 16 KiB stripes) ----
__global__ void k_smax_zero(const float* __restrict__ x, float* __restrict__ ws) {
  __shared__ float sm[4];
  int t = threadIdx.x;  // 256
  int gid = blockIdx.x * 256 + t;        // [0, 65536)
  ws[OFF_RACC + gid] = 0.0f;
  if (gid < 3 * NSPREAD * 1024 - 65536) ws[OFF_RACC + 65536 + gid] = 0.0f;
  if (gid < 3) ((int*)ws)[OFF_CNT + gid] = 0;
  const float4* xb = (const float4*)x + (size_t)blockIdx.x * 16 * 1024;
  float4 v0 = xb[t], v1 = xb[t + 256], v2 = xb[t + 512], v3 = xb[t + 768];
  float m = fmaxf(fmaxf(fmaxf(v0.x, v0.y), fmaxf(v0.z, v0.w)),
                  fmaxf(fmaxf(v1.x, v1.y), fmaxf(v1.z, v1.w)));
  m = fmaxf(m, fmaxf(fmaxf(fmaxf(v2.x, v2.y), fmaxf(v2.z, v2.w)),
                     fmaxf(fmaxf(v3.x, v3.y), fmaxf(v3.z, v3.w))));
  #pragma unroll
  for (int off = 32; off > 0; off >>= 1) m = fmaxf(m, __shfl_xor(m, off, 64));
  if ((t & 63) == 0) sm[t >> 6] = m;
  __syncthreads();
  if (t == 0) {
    m = fmaxf(fmaxf(sm[0], sm[1]), fmaxf(sm[2], sm[3]));
    atomicMax((int*)(ws + OFF_M), __float_as_int(m));  // poison is negative int
  }
}

// ---- K2: E' = bf16(exp((x-M)*20)); R0 atomics; last block -> s, r1 ----
// 1024 blocks x 256; thread t owns cols 4t..4t+3 of 16 rows.
__global__ void k_exp_rowsum(const float* __restrict__ x,
                             unsigned short* __restrict__ Eb,
                             float* __restrict__ ws) {
  __shared__ float sm[4];
  __shared__ float s_sh;
  __shared__ int last_sh;
  int t = threadIdx.x;
  float M = ws[OFF_M];
  float a0 = 0.f, a1 = 0.f, a2 = 0.f, a3 = 0.f;
  const float* xb = x + (size_t)blockIdx.x * 16 * K_COLS + 4 * t;
  unsigned short* eb = Eb + (size_t)blockIdx.x * 16 * K_COLS + 4 * t;
  #pragma unroll 2
  for (int i = 0; i < 4; ++i) {
    float4 v0 = *(const float4*)(xb + (size_t)(4 * i + 0) * K_COLS);
    float4 v1 = *(const float4*)(xb + (size_t)(4 * i + 1) * K_COLS);
    float4 v2 = *(const float4*)(xb + (size_t)(4 * i + 2) * K_COLS);
    float4 v3 = *(const float4*)(xb + (size_t)(4 * i + 3) * K_COLS);
    #pragma unroll
    for (int rr = 0; rr < 4; ++rr) {
      float4 v = (rr == 0) ? v0 : (rr == 1) ? v1 : (rr == 2) ? v2 : v3;
      unsigned h0 = bf16rne(__expf((v.x - M) * INV_EPS));
      unsigned h1 = bf16rne(__expf((v.y - M) * INV_EPS));
      unsigned h2 = bf16rne(__expf((v.z - M) * INV_EPS));
      unsigned h3 = bf16rne(__expf((v.w - M) * INV_EPS));
      ushort4 hs;
      hs.x = (unsigned short)h0; hs.y = (unsigned short)h1;
      hs.z = (unsigned short)h2; hs.w = (unsigned short)h3;
      *(ushort4*)(eb + (size_t)(4 * i + rr) * K_COLS) = hs;
      a0 += bf16tof(h0); a1 += bf16tof(h1); a2 += bf16tof(h2); a3 += bf16tof(h3);
    }
  }
  float* R = ws + OFF_RACC + (blockIdx.x & (NSPREAD - 1)) * 1024;
  atomicAdd(&R[4 * t + 0], a0);
  atomicAdd(&R[4 * t + 1], a1);
  atomicAdd(&R[4 * t + 2], a2);
  atomicAdd(&R[4 * t + 3], a3);

  __threadfence();
  if (t == 0)
    last_sh = (atomicAdd((int*)ws + OFF_CNT + 0, 1) == (int)gridDim.x - 1);
  __syncthreads();
  if (!last_sh) return;
  // fold R0, compute S -> s -> r1
  float f0 = 0.f, f1 = 0.f, f2 = 0.f, f3 = 0.f;
  #pragma unroll 4
  for (int i = 0; i < NSPREAD; ++i) {
    float4 v = *(const float4*)(ws + OFF_RACC + i * 1024 + 4 * t);
    f0 += v.x; f1 += v.y; f2 += v.z; f3 += v.w;
  }
  float p = f0 + f1 + f2 + f3;
  #pragma unroll
  for (int off = 32; off > 0; off >>= 1) p += __shfl_xor(p, off, 64);
  if ((t & 63) == 0) sm[t >> 6] = p;
  __syncthreads();
  if (t == 0) {
    float S = sm[0] + sm[1] + sm[2] + sm[3];
    float s = 1.0f / (S + STAB);
    ws[OFF_S] = s;
    s_sh = s;
  }
  __syncthreads();
  float s = s_sh;
  float4 r4;
  r4.x = 1.0f / ((s * f0 + STAB) * K_COLS);
  r4.y = 1.0f / ((s * f1 + STAB) * K_COLS);
  r4.z = 1.0f / ((s * f2 + STAB) * K_COLS);
  r4.w = 1.0f / ((s * f3 + STAB) * K_COLS);
  *(float4*)(ws + OFF_R + 4 * t) = r4;
}

// ---- K3: col-normalize + next row-sum; last block -> r_next ----
// 1024 blocks x 256; wave owns rows 4w..4w+3; lane owns cols [8l,8l+8) and
// [512+8l,512+8l+8); all 8 uint4 loads issued up front.
__global__ void k_col(const unsigned short* __restrict__ Eb, float* __restrict__ ws,
                      float* __restrict__ Racc, int cnt_idx, int first) {
  __shared__ float lacc[4][1024];
  __shared__ float r_sh[1024];
  __shared__ int last_sh;
  int t = threadIdx.x;
  int lane = t & 63;
  int wv = t >> 6;
  float s = ws[OFF_S];
  ((float4*)r_sh)[t] = ((const float4*)(ws + OFF_R))[t];
  __syncthreads();

  float rv[16];
  {
    float4 ra = *(const float4*)&r_sh[8 * lane];
    float4 rb = *(const float4*)&r_sh[8 * lane + 4];
    float4 rc = *(const float4*)&r_sh[512 + 8 * lane];
    float4 rd = *(const float4*)&r_sh[512 + 8 * lane + 4];
    rv[0] = ra.x; rv[1] = ra.y; rv[2] = ra.z; rv[3] = ra.w;
    rv[4] = rb.x; rv[5] = rb.y; rv[6] = rb.z; rv[7] = rb.w;
    rv[8] = rc.x; rv[9] = rc.y; rv[10] = rc.z; rv[11] = rc.w;
    rv[12] = rd.x; rv[13] = rd.y; rv[14] = rd.z; rv[15] = rd.w;
  }

  int w = blockIdx.x * 4 + wv;          // [0,4096): owns rows 4w..4w+3
  const unsigned short* ebase = Eb + (size_t)(4 * w) * K_COLS + 8 * lane;
  uint4 L[4][2];
  #pragma unroll
  for (int rr = 0; rr < 4; ++rr) {
    L[rr][0] = *(const uint4*)(ebase + (size_t)rr * K_COLS);
    L[rr][1] = *(const uint4*)(ebase + (size_t)rr * K_COLS + 512);
  }

  float acc[16];
  #pragma unroll
  for (int i = 0; i < 16; ++i) acc[i] = 0.f;
  float* c = ws + OFF_C;

  #pragma unroll
  for (int rr = 0; rr < 4; rr += 2) {
    float e0[16], e1[16];
    #pragma unroll
    for (int h = 0; h < 2; ++h) {
      uint4 u = L[rr][h];
      uint4 v = L[rr + 1][h];
      e0[8*h+0] = bf16tof(u.x & 0xFFFFu); e0[8*h+1] = bf16tof(u.x >> 16);
      e0[8*h+2] = bf16tof(u.y & 0xFFFFu); e0[8*h+3] = bf16tof(u.y >> 16);
      e0[8*h+4] = bf16tof(u.z & 0xFFFFu); e0[8*h+5] = bf16tof(u.z >> 16);
      e0[8*h+6] = bf16tof(u.w & 0xFFFFu); e0[8*h+7] = bf16tof(u.w >> 16);
      e1[8*h+0] = bf16tof(v.x & 0xFFFFu); e1[8*h+1] = bf16tof(v.x >> 16);
      e1[8*h+2] = bf16tof(v.y & 0xFFFFu); e1[8*h+3] = bf16tof(v.y >> 16);
      e1[8*h+4] = bf16tof(v.z & 0xFFFFu); e1[8*h+5] = bf16tof(v.z >> 16);
      e1[8*h+6] = bf16tof(v.w & 0xFFFFu); e1[8*h+7] = bf16tof(v.w >> 16);
    }
    float p0 = 0.f, p1 = 0.f;
    #pragma unroll
    for (int i = 0; i < 16; ++i) { p0 += e0[i] * rv[i]; p1 += e1[i] * rv[i]; }
    #pragma unroll
    for (int off = 32; off > 0; off >>= 1) {
      p0 += __shfl_xor(p0, off, 64);
      p1 += __shfl_xor(p1, off, 64);
    }
    int row0 = 4 * w + rr;
    float c0in = first ? 1.0f : c[row0];
    float c1in = first ? 1.0f : c[row0 + 1];
    float c0n = c0in / ((s * c0in * p0 + STAB) * B_ROWS);
    float c1n = c1in / ((s * c1in * p1 + STAB) * B_ROWS);
    if (lane == 0) { c[row0] = c0n; c[row0 + 1] = c1n; }
    #pragma unroll
    for (int i = 0; i < 16; ++i) acc[i] += e0[i] * c0n + e1[i] * c1n;
  }

  *(float4*)&lacc[wv][8 * lane]       = *(float4*)&acc[0];
  *(float4*)&lacc[wv][8 * lane + 4]   = *(float4*)&acc[4];
  *(float4*)&lacc[wv][512 + 8 * lane]     = *(float4*)&acc[8];
  *(float4*)&lacc[wv][512 + 8 * lane + 4] = *(float4*)&acc[12];
  __syncthreads();
  float* Rs = Racc + (blockIdx.x & (NSPREAD - 1)) * 1024;
  #pragma unroll
  for (int j = 0; j < 4; ++j) {
    int col = t + 256 * j;
    atomicAdd(&Rs[col], lacc[0][col] + lacc[1][col] + lacc[2][col] + lacc[3][col]);
  }

  __threadfence();
  if (t == 0)
    last_sh = (atomicAdd((int*)ws + OFF_CNT + cnt_idx, 1) == (int)gridDim.x - 1);
  __syncthreads();
  if (!last_sh) return;
  // fold this pass's R, compute r_next from r_old (still in r_sh)
  float f0 = 0.f, f1 = 0.f, f2 = 0.f, f3 = 0.f;
  #pragma unroll 4
  for (int i = 0; i < NSPREAD; ++i) {
    float4 v = *(const float4*)(Racc + i * 1024 + 4 * t);
    f0 += v.x; f1 += v.y; f2 += v.z; f3 += v.w;
  }
  float4 ro = *(const float4*)&r_sh[4 * t];
  float4 rn;
  rn.x = ro.x / ((s * ro.x * f0 + STAB) * K_COLS);
  rn.y = ro.y / ((s * ro.y * f1 + STAB) * K_COLS);
  rn.z = ro.z / ((s * ro.z * f2 + STAB) * K_COLS);
  rn.w = ro.w / ((s * ro.w * f3 + STAB) * K_COLS);
  *(float4*)(ws + OFF_R + 4 * t) = rn;
}

// ---- K4: final col-normalize + output. 2048 blocks x 256; wave owns 2 rows ----
__global__ void k_final(const unsigned short* __restrict__ Eb,
                        float* __restrict__ ws, float* __restrict__ out) {
  __shared__ float r_sh[1024];
  int t = threadIdx.x;
  int lane = t & 63;
  int wv = t >> 6;
  float s = ws[OFF_S];
  ((float4*)r_sh)[t] = ((const float4*)(ws + OFF_R))[t];
  __syncthreads();

  float rv[16];
  {
    float4 ra = *(const float4*)&r_sh[8 * lane];
    float4 rb = *(const float4*)&r_sh[8 * lane + 4];
    float4 rc = *(const float4*)&r_sh[512 + 8 * lane];
    float4 rd = *(const float4*)&r_sh[512 + 8 * lane + 4];
    rv[0] = ra.x; rv[1] = ra.y; rv[2] = ra.z; rv[3] = ra.w;
    rv[4] = rb.x; rv[5] = rb.y; rv[6] = rb.z; rv[7] = rb.w;
    rv[8] = rc.x; rv[9] = rc.y; rv[10] = rc.z; rv[11] = rc.w;
    rv[12] = rd.x; rv[13] = rd.y; rv[14] = rd.z; rv[15] = rd.w;
  }

  int w = blockIdx.x * 4 + wv;          // owns rows 2w, 2w+1
  const unsigned short* e0p = Eb + (size_t)(2 * w) * K_COLS + 8 * lane;
  const unsigned short* e1p = e0p + K_COLS;
  uint4 A0 = *(const uint4*)(e0p);
  uint4 A1 = *(const uint4*)(e0p + 512);
  uint4 B0 = *(const uint4*)(e1p);
  uint4 B1 = *(const uint4*)(e1p + 512);

  float e0[16], e1[16];
  e0[0]=bf16tof(A0.x&0xFFFFu); e0[1]=bf16tof(A0.x>>16);
  e0[2]=bf16tof(A0.y&0xFFFFu); e0[3]=bf16tof(A0.y>>16);
  e0[4]=bf16tof(A0.z&0xFFFFu); e0[5]=bf16tof(A0.z>>16);
  e0[6]=bf16tof(A0.w&0xFFFFu); e0[7]=bf16tof(A0.w>>16);
  e0[8]=bf16tof(A1.x&0xFFFFu); e0[9]=bf16tof(A1.x>>16);
  e0[10]=bf16tof(A1.y&0xFFFFu); e0[11]=bf16tof(A1.y>>16);
  e0[12]=bf16tof(A1.z&0xFFFFu); e0[13]=bf16tof(A1.z>>16);
  e0[14]=bf16tof(A1.w&0xFFFFu); e0[15]=bf16tof(A1.w>>16);
  e1[0]=bf16tof(B0.x&0xFFFFu); e1[1]=bf16tof(B0.x>>16);
  e1[2]=bf16tof(B0.y&0xFFFFu); e1[3]=bf16tof(B0.y>>16);
  e1[4]=bf16tof(B0.z&0xFFFFu); e1[5]=bf16tof(B0.z>>16);
  e1[6]=bf16tof(B0.w&0xFFFFu); e1[7]=bf16tof(B0.w>>16);
  e1[8]=bf16tof(B1.x&0xFFFFu); e1[9]=bf16tof(B1.x>>16);
  e1[10]=bf16tof(B1.y&0xFFFFu); e1[11]=bf16tof(B1.y>>16);
  e1[12]=bf16tof(B1.z&0xFFFFu); e1[13]=bf16tof(B1.z>>16);
  e1[14]=bf16tof(B1.w&0xFFFFu); e1[15]=bf16tof(B1.w>>16);

  float p0 = 0.f, p1 = 0.f;
  #pragma unroll
  for (int i = 0; i < 16; ++i) { p0 += e0[i] * rv[i]; p1 += e1[i] * rv[i]; }
  #pragma unroll
  for (int off = 32; off > 0; off >>= 1) {
    p0 += __shfl_xor(p0, off, 64);
    p1 += __shfl_xor(p1, off, 64);
  }
  const float* c = ws + OFF_C;
  float c0in = c[2 * w];
  float c1in = c[2 * w + 1];
  float c0n = c0in / ((s * c0in * p0 + STAB) * B_ROWS);
  float c1n = c1in / ((s * c1in * p1 + STAB) * B_ROWS);
  float f0 = s * c0n * B_ROWS;
  float f1 = s * c1n * B_ROWS;

  float* o0 = out + (size_t)(2 * w) * K_COLS + 8 * lane;
  float* o1 = o0 + K_COLS;
  float4 u;
  u.x = e0[0]*rv[0]*f0; u.y = e0[1]*rv[1]*f0; u.z = e0[2]*rv[2]*f0; u.w = e0[3]*rv[3]*f0;
  *(float4*)(o0) = u;
  u.x = e0[4]*rv[4]*f0; u.y = e0[5]*rv[5]*f0; u.z = e0[6]*rv[6]*f0; u.w = e0[7]*rv[7]*f0;
  *(float4*)(o0 + 4) = u;
  u.x = e0[8]*rv[8]*f0; u.y = e0[9]*rv[9]*f0; u.z = e0[10]*rv[10]*f0; u.w = e0[11]*rv[11]*f0;
  *(float4*)(o0 + 512) = u;
  u.x = e0[12]*rv[12]*f0; u.y = e0[13]*rv[13]*f0; u.z = e0[14]*rv[14]*f0; u.w = e0[15]*rv[15]*f0;
  *(float4*)(o0 + 516) = u;
  u.x = e1[0]*rv[0]*f1; u.y = e1[1]*rv[1]*f1; u.z = e1[2]*rv[2]*f1; u.w = e1[3]*rv[3]*f1;
  *(float4*)(o1) = u;
  u.x = e1[4]*rv[4]*f1; u.y = e1[5]*rv[5]*f1; u.z = e1[6]*rv[6]*f1; u.w = e1[7]*rv[7]*f1;
  *(float4*)(o1 + 4) = u;
  u.x = e1[8]*rv[8]*f1; u.y = e1[9]*rv[9]*f1; u.z = e1[10]*rv[10]*f1; u.w = e1[11]*rv[11]*f1;
  *(float4*)(o1 + 512) = u;
  u.x = e1[12]*rv[12]*f1; u.y = e1[13]*rv[13]*f1; u.z = e1[14]*rv[14]*f1; u.w = e1[15]*rv[15]*f1;
  *(float4*)(o1 + 516) = u;
}

extern "C" void kernel_launch(void* const* d_in, const int* in_sizes, int n_in,
                              void* d_out, int out_size, void* d_ws, size_t ws_size,
                              hipStream_t stream) {
  const float* x = (const float*)d_in[0];
  float* out = (float*)d_out;
  float* ws = (float*)d_ws;
  unsigned short* Eb = (unsigned short*)((char*)d_ws + EB_BYTE_OFF);
  (void)in_sizes; (void)n_in; (void)out_size; (void)ws_size;

  float* R1 = ws + OFF_RACC + NSPREAD * 1024;
  float* R2 = ws + OFF_RACC + 2 * NSPREAD * 1024;

  k_smax_zero<<<256, 256, 0, stream>>>(x, ws);
  k_exp_rowsum<<<1024, 256, 0, stream>>>(x, Eb, ws);   // E', R0, (s, r1)
  k_col<<<1024, 256, 0, stream>>>(Eb, ws, R1, 1, 1);   // c1, R1, (r2)
  k_col<<<1024, 256, 0, stream>>>(Eb, ws, R2, 2, 0);   // c2, R2, (r3)
  k_final<<<2048, 256, 0, stream>>>(Eb, ws, out);      // c3 + output
}

// Round 7
// 156.153 us; speedup vs baseline: 3.0569x; 3.0569x over previous
//
#include <hip/hip_runtime.h>
#include <math.h>

// StableSinkhornKnopp: B=16384 x K=1024 fp32.
// Q[k,b] = s * E[b,k] * r[k] * c[b],  E = exp((x-M')*20), M' = sampled max
// (max shift cancels in all normalizations). E cached once as bf16 (32 MiB).
// R6 lesson: __threadfence (device-scope) on gfx950 = per-wave L2
// writeback across XCDs -> 4x regression. Kernel boundaries are the only
// cheap grid sync. So: 5 launches, and each consumer kernel re-derives
// s/r redundantly per block from the previous kernel's atomic partials
// (fixed fold order -> bitwise identical in every block; no fences).
//   K1 smax+zero -> K2 exp+R0 -> K3 col(ngen=1): c1,R1
//   -> K3 col(ngen=2): c2,R2 -> K4 final(ngen=3): c3 + out.

namespace {
constexpr int B_ROWS = 16384;
constexpr int K_COLS = 1024;
constexpr float INV_EPS = 20.0f;   // 1/0.05
constexpr float STAB = 1e-9f;
constexpr int NSPREAD = 16;        // atomic accumulator spread (R3-validated)

// ws float offsets
constexpr int OFF_M    = 0;        // sampled max (int-ordered float)
constexpr int OFF_RACC = 2048;     // 3 x NSPREAD x 1024 = 49152 floats
constexpr int OFF_C    = 51200;    // c vector, 16384 (ends 67584)
constexpr size_t EB_BYTE_OFF = 1u << 20;  // bf16 E at ws+1MiB, 32 MiB
}

__device__ inline unsigned bf16rne(float f) {   // round-to-nearest-even bf16
  unsigned u = __float_as_uint(f);
  return (u + 0x7FFFu + ((u >> 16) & 1u)) >> 16;
}
__device__ inline float bf16tof(unsigned h) { return __uint_as_float(h << 16); }

// Fold RACC generations 0..ngen-1 -> s and r_ngen, identically in every
// block. Thread t owns cols 4t..4t+3. Writes r into r_sh[1024]; returns s.
__device__ float derive_r(const float* __restrict__ ws, float* __restrict__ r_sh,
                          float* __restrict__ red4, int ngen) {
  int t = threadIdx.x;            // 256
  int lane = t & 63, wv = t >> 6;
  // generation 0 fold
  float f0 = 0.f, f1 = 0.f, f2 = 0.f, f3 = 0.f;
  #pragma unroll 4
  for (int i = 0; i < NSPREAD; ++i) {
    float4 v = *(const float4*)(ws + OFF_RACC + i * 1024 + 4 * t);
    f0 += v.x; f1 += v.y; f2 += v.z; f3 += v.w;
  }
  float p = f0 + f1 + f2 + f3;
  #pragma unroll
  for (int off = 32; off > 0; off >>= 1) p += __shfl_xor(p, off, 64);
  if (lane == 0) red4[wv] = p;
  __syncthreads();
  float S = red4[0] + red4[1] + red4[2] + red4[3];  // same in all threads
  float s = 1.0f / (S + STAB);
  float4 r;
  r.x = 1.0f / ((s * f0 + STAB) * K_COLS);
  r.y = 1.0f / ((s * f1 + STAB) * K_COLS);
  r.z = 1.0f / ((s * f2 + STAB) * K_COLS);
  r.w = 1.0f / ((s * f3 + STAB) * K_COLS);
  for (int g = 1; g < ngen; ++g) {
    const float* base = ws + OFF_RACC + g * NSPREAD * 1024;
    f0 = f1 = f2 = f3 = 0.f;
    #pragma unroll 4
    for (int i = 0; i < NSPREAD; ++i) {
      float4 v = *(const float4*)(base + i * 1024 + 4 * t);
      f0 += v.x; f1 += v.y; f2 += v.z; f3 += v.w;
    }
    r.x = r.x / ((s * r.x * f0 + STAB) * K_COLS);
    r.y = r.y / ((s * r.y * f1 + STAB) * K_COLS);
    r.z = r.z / ((s * r.z * f2 + STAB) * K_COLS);
    r.w = r.w / ((s * r.w * f3 + STAB) * K_COLS);
  }
  *(float4*)(r_sh + 4 * t) = r;
  __syncthreads();
  return s;
}

// ---- K1: zero RACC, sampled max (4 MiB in 16 KiB stripes). 256 x 256 ----
__global__ void k_smax_zero(const float* __restrict__ x, float* __restrict__ ws) {
  __shared__ float sm[4];
  int t = threadIdx.x;
  int gid = blockIdx.x * 256 + t;        // [0, 65536)
  if (gid < 3 * NSPREAD * 1024) ws[OFF_RACC + gid] = 0.0f;
  const float4* xb = (const float4*)x + (size_t)blockIdx.x * 16 * 1024;
  float4 v0 = xb[t], v1 = xb[t + 256], v2 = xb[t + 512], v3 = xb[t + 768];
  float m = fmaxf(fmaxf(fmaxf(v0.x, v0.y), fmaxf(v0.z, v0.w)),
                  fmaxf(fmaxf(v1.x, v1.y), fmaxf(v1.z, v1.w)));
  m = fmaxf(m, fmaxf(fmaxf(fmaxf(v2.x, v2.y), fmaxf(v2.z, v2.w)),
                     fmaxf(fmaxf(v3.x, v3.y), fmaxf(v3.z, v3.w))));
  #pragma unroll
  for (int off = 32; off > 0; off >>= 1) m = fmaxf(m, __shfl_xor(m, off, 64));
  if ((t & 63) == 0) sm[t >> 6] = m;
  __syncthreads();
  if (t == 0) {
    m = fmaxf(fmaxf(sm[0], sm[1]), fmaxf(sm[2], sm[3]));
    atomicMax((int*)(ws + OFF_M), __float_as_int(m));  // poison is negative int
  }
}

// ---- K2: E' = bf16(exp((x-M)*20)); R0 atomics. 512 x 256 (R3 body) ----
__global__ void k_exp_rowsum(const float* __restrict__ x,
                             unsigned short* __restrict__ Eb,
                             float* __restrict__ ws) {
  int t = threadIdx.x;  // thread owns cols 4t..4t+3 of 32 rows
  float M = ws[OFF_M];
  float a0 = 0.f, a1 = 0.f, a2 = 0.f, a3 = 0.f;
  const float* xb = x + (size_t)blockIdx.x * 32 * K_COLS + 4 * t;
  unsigned short* eb = Eb + (size_t)blockIdx.x * 32 * K_COLS + 4 * t;
  #pragma unroll 2
  for (int i = 0; i < 8; ++i) {
    float4 v0 = *(const float4*)(xb + (size_t)(4 * i + 0) * K_COLS);
    float4 v1 = *(const float4*)(xb + (size_t)(4 * i + 1) * K_COLS);
    float4 v2 = *(const float4*)(xb + (size_t)(4 * i + 2) * K_COLS);
    float4 v3 = *(const float4*)(xb + (size_t)(4 * i + 3) * K_COLS);
    #pragma unroll
    for (int rr = 0; rr < 4; ++rr) {
      float4 v = (rr == 0) ? v0 : (rr == 1) ? v1 : (rr == 2) ? v2 : v3;
      unsigned h0 = bf16rne(__expf((v.x - M) * INV_EPS));
      unsigned h1 = bf16rne(__expf((v.y - M) * INV_EPS));
      unsigned h2 = bf16rne(__expf((v.z - M) * INV_EPS));
      unsigned h3 = bf16rne(__expf((v.w - M) * INV_EPS));
      ushort4 hs;
      hs.x = (unsigned short)h0; hs.y = (unsigned short)h1;
      hs.z = (unsigned short)h2; hs.w = (unsigned short)h3;
      *(ushort4*)(eb + (size_t)(4 * i + rr) * K_COLS) = hs;
      a0 += bf16tof(h0); a1 += bf16tof(h1); a2 += bf16tof(h2); a3 += bf16tof(h3);
    }
  }
  float* R = ws + OFF_RACC + (blockIdx.x & (NSPREAD - 1)) * 1024;
  atomicAdd(&R[4 * t + 0], a0);
  atomicAdd(&R[4 * t + 1], a1);
  atomicAdd(&R[4 * t + 2], a2);
  atomicAdd(&R[4 * t + 3], a3);
}

// ---- K3: prologue derive_r(ngen) -> col-normalize + next row-sum ----
// 512 x 256 (R3 body): wave owns 8 rows, 2-row steps, lane cols {4l+256j}
__global__ void k_col(const unsigned short* __restrict__ Eb, float* __restrict__ ws,
                      float* __restrict__ Racc, int ngen, int first) {
  __shared__ float lacc[4][1024];
  __shared__ float r_sh[1024];
  __shared__ float red4[4];
  int t = threadIdx.x;
  int lane = t & 63;
  int wv = t >> 6;
  float s = derive_r(ws, r_sh, red4, ngen);

  float rv[16];
  #pragma unroll
  for (int j = 0; j < 4; ++j) {
    float4 r4 = *(const float4*)&r_sh[256 * j + 4 * lane];
    rv[4*j+0] = r4.x; rv[4*j+1] = r4.y; rv[4*j+2] = r4.z; rv[4*j+3] = r4.w;
  }
  float acc[16];
  #pragma unroll
  for (int i = 0; i < 16; ++i) acc[i] = 0.f;
  float* c = ws + OFF_C;

  int w = blockIdx.x * 4 + wv;          // [0,2048): owns rows [8w, 8w+8)
  const unsigned short* ew = Eb + (size_t)w * 8 * K_COLS + 4 * lane;

  #pragma unroll 1
  for (int it = 0; it < 4; ++it) {
    const unsigned short* e0p = ew + (size_t)(2 * it) * K_COLS;
    const unsigned short* e1p = e0p + K_COLS;
    uint2 u0 = *(const uint2*)(e0p + 0);
    uint2 u1 = *(const uint2*)(e0p + 256);
    uint2 u2 = *(const uint2*)(e0p + 512);
    uint2 u3 = *(const uint2*)(e0p + 768);
    uint2 w0 = *(const uint2*)(e1p + 0);
    uint2 w1 = *(const uint2*)(e1p + 256);
    uint2 w2 = *(const uint2*)(e1p + 512);
    uint2 w3 = *(const uint2*)(e1p + 768);
    float e0[16], e1[16];
    #pragma unroll
    for (int j = 0; j < 4; ++j) {
      uint2 u = (j == 0) ? u0 : (j == 1) ? u1 : (j == 2) ? u2 : u3;
      uint2 v = (j == 0) ? w0 : (j == 1) ? w1 : (j == 2) ? w2 : w3;
      e0[4*j+0] = bf16tof(u.x & 0xFFFFu); e0[4*j+1] = bf16tof(u.x >> 16);
      e0[4*j+2] = bf16tof(u.y & 0xFFFFu); e0[4*j+3] = bf16tof(u.y >> 16);
      e1[4*j+0] = bf16tof(v.x & 0xFFFFu); e1[4*j+1] = bf16tof(v.x >> 16);
      e1[4*j+2] = bf16tof(v.y & 0xFFFFu); e1[4*j+3] = bf16tof(v.y >> 16);
    }
    float p0 = 0.f, p1 = 0.f;
    #pragma unroll
    for (int i = 0; i < 16; ++i) { p0 += e0[i] * rv[i]; p1 += e1[i] * rv[i]; }
    #pragma unroll
    for (int off = 32; off > 0; off >>= 1) {
      p0 += __shfl_xor(p0, off, 64);
      p1 += __shfl_xor(p1, off, 64);
    }
    int row0 = 8 * w + 2 * it;
    float c0in = first ? 1.0f : c[row0];
    float c1in = first ? 1.0f : c[row0 + 1];
    float c0n = c0in / ((s * c0in * p0 + STAB) * B_ROWS);
    float c1n = c1in / ((s * c1in * p1 + STAB) * B_ROWS);
    if (lane == 0) { c[row0] = c0n; c[row0 + 1] = c1n; }
    #pragma unroll
    for (int i = 0; i < 16; ++i) acc[i] += e0[i] * c0n + e1[i] * c1n;
  }

  #pragma unroll
  for (int j = 0; j < 4; ++j)
    #pragma unroll
    for (int q = 0; q < 4; ++q)
      lacc[wv][256 * j + 4 * lane + q] = acc[4 * j + q];
  __syncthreads();
  float* Rs = Racc + (blockIdx.x & (NSPREAD - 1)) * 1024;
  #pragma unroll
  for (int j = 0; j < 4; ++j) {
    int col = t + 256 * j;
    atomicAdd(&Rs[col], lacc[0][col] + lacc[1][col] + lacc[2][col] + lacc[3][col]);
  }
}

// ---- K4: prologue derive_r(3) -> final col-normalize + output. 512 x 256 ----
__global__ void k_final(const unsigned short* __restrict__ Eb,
                        float* __restrict__ ws, float* __restrict__ out) {
  __shared__ float r_sh[1024];
  __shared__ float red4[4];
  int t = threadIdx.x;
  int lane = t & 63;
  int wv = t >> 6;
  float s = derive_r(ws, r_sh, red4, 3);

  float rv[16];
  #pragma unroll
  for (int j = 0; j < 4; ++j) {
    float4 r4 = *(const float4*)&r_sh[256 * j + 4 * lane];
    rv[4*j+0] = r4.x; rv[4*j+1] = r4.y; rv[4*j+2] = r4.z; rv[4*j+3] = r4.w;
  }
  const float* c = ws + OFF_C;

  int w = blockIdx.x * 4 + wv;          // [0,2048): owns rows [8w, 8w+8)
  const unsigned short* ew = Eb + (size_t)w * 8 * K_COLS + 4 * lane;
  float* ow = out + (size_t)w * 8 * K_COLS + 4 * lane;

  #pragma unroll 1
  for (int it = 0; it < 4; ++it) {
    const unsigned short* e0p = ew + (size_t)(2 * it) * K_COLS;
    const unsigned short* e1p = e0p + K_COLS;
    uint2 u0 = *(const uint2*)(e0p + 0);
    uint2 u1 = *(const uint2*)(e0p + 256);
    uint2 u2 = *(const uint2*)(e0p + 512);
    uint2 u3 = *(const uint2*)(e0p + 768);
    uint2 w0 = *(const uint2*)(e1p + 0);
    uint2 w1 = *(const uint2*)(e1p + 256);
    uint2 w2 = *(const uint2*)(e1p + 512);
    uint2 w3 = *(const uint2*)(e1p + 768);
    float e0[16], e1[16];
    #pragma unroll
    for (int j = 0; j < 4; ++j) {
      uint2 u = (j == 0) ? u0 : (j == 1) ? u1 : (j == 2) ? u2 : u3;
      uint2 v = (j == 0) ? w0 : (j == 1) ? w1 : (j == 2) ? w2 : w3;
      e0[4*j+0] = bf16tof(u.x & 0xFFFFu); e0[4*j+1] = bf16tof(u.x >> 16);
      e0[4*j+2] = bf16tof(u.y & 0xFFFFu); e0[4*j+3] = bf16tof(u.y >> 16);
      e1[4*j+0] = bf16tof(v.x & 0xFFFFu); e1[4*j+1] = bf16tof(v.x >> 16);
      e1[4*j+2] = bf16tof(v.y & 0xFFFFu); e1[4*j+3] = bf16tof(v.y >> 16);
    }
    float p0 = 0.f, p1 = 0.f;
    #pragma unroll
    for (int i = 0; i < 16; ++i) { p0 += e0[i] * rv[i]; p1 += e1[i] * rv[i]; }
    #pragma unroll
    for (int off = 32; off > 0; off >>= 1) {
      p0 += __shfl_xor(p0, off, 64);
      p1 += __shfl_xor(p1, off, 64);
    }
    int row0 = 8 * w + 2 * it;
    float c0in = c[row0];
    float c1in = c[row0 + 1];
    float c0n = c0in / ((s * c0in * p0 + STAB) * B_ROWS);
    float c1n = c1in / ((s * c1in * p1 + STAB) * B_ROWS);
    float f0 = s * c0n * B_ROWS;
    float f1 = s * c1n * B_ROWS;
    float* o0 = ow + (size_t)(2 * it) * K_COLS;
    float* o1 = o0 + K_COLS;
    #pragma unroll
    for (int j = 0; j < 4; ++j) {
      float4 a, b;
      a.x = e0[4*j+0] * rv[4*j+0] * f0; a.y = e0[4*j+1] * rv[4*j+1] * f0;
      a.z = e0[4*j+2] * rv[4*j+2] * f0; a.w = e0[4*j+3] * rv[4*j+3] * f0;
      b.x = e1[4*j+0] * rv[4*j+0] * f1; b.y = e1[4*j+1] * rv[4*j+1] * f1;
      b.z = e1[4*j+2] * rv[4*j+2] * f1; b.w = e1[4*j+3] * rv[4*j+3] * f1;
      *(float4*)(o0 + 256 * j) = a;
      *(float4*)(o1 + 256 * j) = b;
    }
  }
}

extern "C" void kernel_launch(void* const* d_in, const int* in_sizes, int n_in,
                              void* d_out, int out_size, void* d_ws, size_t ws_size,
                              hipStream_t stream) {
  const float* x = (const float*)d_in[0];
  float* out = (float*)d_out;
  float* ws = (float*)d_ws;
  unsigned short* Eb = (unsigned short*)((char*)d_ws + EB_BYTE_OFF);
  (void)in_sizes; (void)n_in; (void)out_size; (void)ws_size;

  float* R1 = ws + OFF_RACC + NSPREAD * 1024;
  float* R2 = ws + OFF_RACC + 2 * NSPREAD * 1024;

  k_smax_zero<<<256, 256, 0, stream>>>(x, ws);
  k_exp_rowsum<<<512, 256, 0, stream>>>(x, Eb, ws);      // E', R0
  k_col<<<512, 256, 0, stream>>>(Eb, ws, R1, 1, 1);      // s,r1 -> c1, R1
  k_col<<<512, 256, 0, stream>>>(Eb, ws, R2, 2, 0);      // r2   -> c2, R2
  k_final<<<512, 256, 0, stream>>>(Eb, ws, out);         // r3   -> c3 + out
}